// Round 2
// baseline (3165.765 us; speedup 1.0000x reference)
//
#include <hip/hip_runtime.h>
#include <hip/hip_bf16.h>

#define H 128
#define LNUM 4
#define NN 4096
#define SS 8192
#define SKK 262144
#define EI 1048576
#define EG 65536
#define NGRAPH 64

typedef unsigned short u16;
typedef unsigned int u32;

__device__ __forceinline__ float b2f(u32 u){ return __uint_as_float(u<<16); }
__device__ __forceinline__ u16 f2b(float f){
  union { __hip_bfloat16 b; u16 u; } x;
  x.b=__float2bfloat16(f);
  return x.u;
}
__device__ __forceinline__ void unp8(uint4 v, float* f){
  f[0]=b2f(v.x&0xFFFF); f[1]=b2f(v.x>>16);
  f[2]=b2f(v.y&0xFFFF); f[3]=b2f(v.y>>16);
  f[4]=b2f(v.z&0xFFFF); f[5]=b2f(v.z>>16);
  f[6]=b2f(v.w&0xFFFF); f[7]=b2f(v.w>>16);
}
__device__ __forceinline__ uint4 pk8(const float* f){
  uint4 r;
  r.x=(u32)f2b(f[0])|((u32)f2b(f[1])<<16);
  r.y=(u32)f2b(f[2])|((u32)f2b(f[3])<<16);
  r.z=(u32)f2b(f[4])|((u32)f2b(f[5])<<16);
  r.w=(u32)f2b(f[6])|((u32)f2b(f[7])<<16);
  return r;
}

struct CvtArgs {
  const void* p[26];
  int start[27];
};

// ---- dtype sniff: bf16 data -> tiny exponents; f32-as-u16 -> ~half big
__global__ void k_sniff(const u16* __restrict__ a, int* __restrict__ flag){
  __shared__ int cnt;
  if(threadIdx.x==0) cnt=0;
  __syncthreads();
  int big=0;
  for(int i=threadIdx.x;i<2048;i+=256){
    int e=(a[i]>>7)&0xFF;
    if(e>=127) big++;
  }
  atomicAdd(&cnt,big);
  __syncthreads();
  if(threadIdx.x==0) *flag=(cnt<16)?1:0;   // 1 => bf16 inputs
}

__global__ void k_convert(CvtArgs args, const int* __restrict__ flag, float* __restrict__ dst){
  int fl=*flag;
  int total=args.start[26];
  for(int i=blockIdx.x*blockDim.x+threadIdx.x;i<total;i+=gridDim.x*blockDim.x){
    int a=0;
    while(args.start[a+1]<=i) a++;
    int j=i-args.start[a];
    float v;
    if(fl) v=b2f(((const u16*)args.p[a])[j]);
    else   v=((const float*)args.p[a])[j];
    dst[i]=v;
  }
}

// ---- edge bucketing
__global__ void k_hist(const int* __restrict__ idx, int n, int shift, int* __restrict__ cnt){
  for(int i=blockIdx.x*blockDim.x+threadIdx.x;i<n;i+=gridDim.x*blockDim.x)
    atomicAdd(&cnt[idx[i]>>shift],1);
}

__global__ void k_scan(const int* __restrict__ cnt, int* __restrict__ off, int nbins){
  __shared__ int ts[1024];
  int t=threadIdx.x;
  int per=nbins>>10;
  int base=t*per;
  int s=0;
  for(int j=0;j<per;j++) s+=cnt[base+j];
  ts[t]=s;
  __syncthreads();
  for(int d=1;d<1024;d<<=1){
    int v=(t>=d)?ts[t-d]:0;
    __syncthreads();
    ts[t]+=v;
    __syncthreads();
  }
  int ex=(t==0)?0:ts[t-1];
  for(int j=0;j<per;j++){ off[base+j]=ex; ex+=cnt[base+j]; }
}

__global__ void k_scatter_i(const int* __restrict__ ei, const int* __restrict__ ea,
                            const int* __restrict__ off, int* __restrict__ cur, int* __restrict__ pack){
  for(int i=blockIdx.x*blockDim.x+threadIdx.x;i<EI;i+=gridDim.x*blockDim.x){
    int s=ei[i], d=ei[EI+i];
    int sub=d>>5;
    int pos=off[sub]+atomicAdd(&cur[sub],1);
    pack[pos]=((s&31)<<9)|((d&31)<<4)|(ea[i]&15);
  }
}

__global__ void k_scatter_g(const int* __restrict__ ei, const int* __restrict__ ea,
                            const int* __restrict__ off, int* __restrict__ cur, int* __restrict__ pack){
  for(int i=blockIdx.x*blockDim.x+threadIdx.x;i<EG;i+=gridDim.x*blockDim.x){
    int s=ei[i], d=ei[EG+i];
    int pos=off[d]+atomicAdd(&cur[d],1);
    pack[pos]=(s<<4)|(ea[i]&15);
  }
}

// ---- rf = relu(rwse @ rwse_w + rwse_b)   (f32, small)
__global__ __launch_bounds__(128) void k_rwse(const float* __restrict__ rwse, const float* __restrict__ w,
                      const float* __restrict__ b, float* __restrict__ rf){
  __shared__ float ws[16*128];
  __shared__ float rv[16];
  int n=blockIdx.x, c=threadIdx.x;
  for(int i=c;i<2048;i+=128) ws[i]=w[i];
  if(c<16) rv[c]=rwse[n*16+c];
  __syncthreads();
  float acc=b[c];
  for(int j=0;j<16;j++) acc=fmaf(rv[j],ws[j*128+c],acc);
  rf[(size_t)n*H+c]=fmaxf(acc,0.f);
}

// ---- h0 = (atom[x_ids] + rf[node_ids]) * valid  -> bf16
__global__ void k_h0(const float* __restrict__ atom, const float* __restrict__ rf,
                     const int* __restrict__ xids, const int* __restrict__ nids,
                     const int* __restrict__ valid, u16* __restrict__ h){
  int i=blockIdx.x*blockDim.x+threadIdx.x;   // SKK*16 groups of 8
  if(i>=SKK*16) return;
  int r=i>>4, q=i&15;
  const float4* ap=(const float4*)(atom+(size_t)xids[r]*H)+q*2;
  const float4* bp=(const float4*)(rf+(size_t)nids[r]*H)+q*2;
  float4 a0=ap[0],a1=ap[1],b0=bp[0],b1=bp[1];
  float vm=valid[r]?1.f:0.f;
  float f[8]={(a0.x+b0.x)*vm,(a0.y+b0.y)*vm,(a0.z+b0.z)*vm,(a0.w+b0.w)*vm,
              (a1.x+b1.x)*vm,(a1.y+b1.y)*vm,(a1.z+b1.z)*vm,(a1.w+b1.w)*vm};
  ((uint4*)h)[i]=pk8(f);
}

// ---- local GINE aggregation per subgraph
__global__ __launch_bounds__(128) void k_local_agg(const u16* __restrict__ h, const float* __restrict__ be,
                           const int* __restrict__ eoff, const int* __restrict__ ecnt,
                           const int* __restrict__ epack, const float* __restrict__ epsp, int layer,
                           u16* __restrict__ hh){
  __shared__ float hs[32][128];
  __shared__ float ag[32][128];
  __shared__ float bes[16][128];
  int sub=blockIdx.x, c=threadIdx.x;
  size_t base=(size_t)sub*32*H;
  for(int r=0;r<32;r++){ hs[r][c]=b2f(h[base+r*H+c]); ag[r][c]=0.f; }
  for(int i=0;i<16;i++) bes[i][c]=be[i*128+c];
  __syncthreads();
  int o=eoff[sub], e=o+ecnt[sub];
  for(;o<e;o++){
    int p=epack[o];
    int sl=p>>9, dl=(p>>4)&31, ea=p&15;
    ag[dl][c]+=fmaxf(hs[sl][c]+bes[ea][c],0.f);
  }
  __syncthreads();
  float ep=1.f+epsp[layer];
  for(int r=0;r<32;r++) hh[base+r*H+c]=f2b(fmaf(ep,hs[r][c],ag[r][c]));
}

// ---- 128->128 GEMM over bf16 rows, fused epilogues (f32 accumulate)
// MODE 0: out = A@W
// MODE 1: out = relu(A@W+bias)
// MODE 2: out = relu(A@W+bias) + column stats atomics
// MODE 3: out = gelu((A*s+t)@W + bias + rowbias[row>>6])
// MODE 4: v = A@W+bias; row-LN; out = (res + v)*valid
template<int MODE>
__global__ __launch_bounds__(256) void k_gemm(
    const u16* __restrict__ A, const float* __restrict__ W,
    const float* __restrict__ bias, u16* __restrict__ out,
    const float* __restrict__ saff, const float* __restrict__ taff,
    const u16* __restrict__ rowbias,
    float* __restrict__ stats,
    const u16* __restrict__ res, const int* __restrict__ validv,
    const float* __restrict__ lng, const float* __restrict__ lnb)
{
  __shared__ float As[64][132];
  __shared__ float Ws[32][132];
  __shared__ float mu_s[64], rs_s[64];
  int row0=blockIdx.x*64;
  int t=threadIdx.x;
  int rg=t>>4, cg=t&15;
  // stage A tile bf16 -> f32 (optional BN affine for MODE 3)
  {
    int r=t>>2, q=t&3;
    const uint4* Ap=(const uint4*)(A+(size_t)(row0+r)*H);
    #pragma unroll
    for(int j=0;j<4;j++){
      int ch=q+j*4;
      float f[8];
      unp8(Ap[ch],f);
      if(MODE==3){
        #pragma unroll
        for(int e=0;e<8;e++){ int col=ch*8+e; f[e]=fmaf(f[e],saff[col],taff[col]); }
      }
      #pragma unroll
      for(int e=0;e<8;e++) As[r][ch*8+e]=f[e];
    }
  }
  float acc[4][8];
  #pragma unroll
  for(int i=0;i<4;i++)
    #pragma unroll
    for(int j=0;j<8;j++) acc[i][j]=0.f;

  for(int kc=0;kc<4;kc++){
    __syncthreads();
    {
      int r=t>>3, q=t&7;
      const float4* Wp=(const float4*)(W+(size_t)(kc*32+r)*H);
      #pragma unroll
      for(int j=0;j<4;j++){
        int kq=q+j*8;
        float4 v=Wp[kq];
        Ws[r][kq*4+0]=v.x; Ws[r][kq*4+1]=v.y; Ws[r][kq*4+2]=v.z; Ws[r][kq*4+3]=v.w;
      }
    }
    __syncthreads();
    #pragma unroll 4
    for(int k=0;k<32;k++){
      float av[4];
      #pragma unroll
      for(int i=0;i<4;i++) av[i]=As[rg*4+i][kc*32+k];
      float4 b0=*(const float4*)&Ws[k][cg*8];
      float4 b1=*(const float4*)&Ws[k][cg*8+4];
      #pragma unroll
      for(int i=0;i<4;i++){
        acc[i][0]=fmaf(av[i],b0.x,acc[i][0]);
        acc[i][1]=fmaf(av[i],b0.y,acc[i][1]);
        acc[i][2]=fmaf(av[i],b0.z,acc[i][2]);
        acc[i][3]=fmaf(av[i],b0.w,acc[i][3]);
        acc[i][4]=fmaf(av[i],b1.x,acc[i][4]);
        acc[i][5]=fmaf(av[i],b1.y,acc[i][5]);
        acc[i][6]=fmaf(av[i],b1.z,acc[i][6]);
        acc[i][7]=fmaf(av[i],b1.w,acc[i][7]);
      }
    }
  }

  int cbase=cg*8;
  float bj[8];
  #pragma unroll
  for(int j=0;j<8;j++) bj[j]=bias?bias[cbase+j]:0.f;
  #pragma unroll
  for(int i=0;i<4;i++)
    #pragma unroll
    for(int j=0;j<8;j++) acc[i][j]+=bj[j];

  if(MODE==3){
    float rb[8];
    int nb=row0>>6;
    unp8(*(const uint4*)(rowbias+(size_t)nb*H+cbase), rb);
    #pragma unroll
    for(int i=0;i<4;i++)
      #pragma unroll
      for(int j=0;j<8;j++){
        float x=acc[i][j]+rb[j];
        acc[i][j]=0.5f*x*(1.f+erff(x*0.70710678118654752f));
      }
  }
  if(MODE==1||MODE==2){
    #pragma unroll
    for(int i=0;i<4;i++)
      #pragma unroll
      for(int j=0;j<8;j++) acc[i][j]=fmaxf(acc[i][j],0.f);
  }

  if(MODE==4){
    __syncthreads();
    #pragma unroll
    for(int i=0;i<4;i++)
      #pragma unroll
      for(int j=0;j<8;j++) As[rg*4+i][cbase+j]=acc[i][j];
    __syncthreads();
    if(t<64){
      const float4* row=(const float4*)&As[t][0];
      float s=0.f,q=0.f;
      for(int j4=0;j4<32;j4++){
        float4 v=row[j4];
        s+=v.x+v.y+v.z+v.w;
        q+=v.x*v.x+v.y*v.y+v.z*v.z+v.w*v.w;
      }
      float mu=s*(1.f/128.f);
      float var=q*(1.f/128.f)-mu*mu;
      mu_s[t]=mu; rs_s[t]=rsqrtf(var+1e-5f);
    }
    __syncthreads();
    #pragma unroll
    for(int i=0;i<4;i++){
      int r=rg*4+i, grow=row0+r;
      float vm=validv[grow]?1.f:0.f;
      float mu=mu_s[r], rs=rs_s[r];
      float ov[8];
      #pragma unroll
      for(int j=0;j<8;j++){
        int cc=cbase+j;
        float v=(acc[i][j]-mu)*rs*lng[cc]+lnb[cc];
        ov[j]=(b2f(res[(size_t)grow*H+cc])+v)*vm;
      }
      *(uint4*)(out+(size_t)grow*H+cbase)=pk8(ov);
    }
  } else {
    #pragma unroll
    for(int i=0;i<4;i++){
      int grow=row0+rg*4+i;
      *(uint4*)(out+(size_t)grow*H+cbase)=pk8(acc[i]);
    }
    if(MODE==2){
      __syncthreads();
      float* red=&Ws[0][0];
      red[t]=0.f;
      __syncthreads();
      #pragma unroll
      for(int j=0;j<8;j++){
        float s=0.f,q=0.f;
        #pragma unroll
        for(int i=0;i<4;i++){ float v=acc[i][j]; s+=v; q+=v*v; }
        atomicAdd(&red[cbase+j],s);
        atomicAdd(&red[128+cbase+j],q);
      }
      __syncthreads();
      if(t<128){
        atomicAdd(&stats[t],red[t]);
        atomicAdd(&stats[128+t],red[128+t]);
      }
    }
  }
}

// ---- BN stats -> per-column affine
__global__ void k_bnfin(const float* __restrict__ stl, const float* __restrict__ stg,
                        const float* __restrict__ gl, const float* __restrict__ bl,
                        const float* __restrict__ gg, const float* __restrict__ bg,
                        float* __restrict__ bnl, float* __restrict__ bnG){
  int c=threadIdx.x;
  {
    float mu=stl[c]*(1.f/262144.f);
    float var=stl[128+c]*(1.f/262144.f)-mu*mu;
    float s=gl[c]*rsqrtf(var+1e-5f);
    bnl[c]=s; bnl[128+c]=bl[c]-mu*s;
  }
  {
    float mu=stg[c]*(1.f/4096.f);
    float var=stg[128+c]*(1.f/4096.f)-mu*mu;
    float s=gg[c]*rsqrtf(var+1e-5f);
    bnG[c]=s; bnG[128+c]=bg[c]-mu*s;
  }
}

// ---- h_node = mean of two root rows (bf16 in/out)
__global__ void k_npool(const u16* __restrict__ h, u16* __restrict__ hn){
  int i=blockIdx.x*blockDim.x+threadIdx.x;  // NN*16 groups of 8
  if(i>=NN*16) return;
  int n=i>>4, q=i&15;
  const uint4* hp=(const uint4*)h;
  float a[8],b[8],o[8];
  unp8(hp[(size_t)n*1024+q],a);
  unp8(hp[(size_t)n*1024+512+q],b);
  #pragma unroll
  for(int e=0;e<8;e++) o[e]=(a[e]+b[e])*0.5f;
  ((uint4*)hn)[i]=pk8(o);
}

// ---- global GINE aggregation per node
__global__ __launch_bounds__(128) void k_gagg(const u16* __restrict__ hn, const float* __restrict__ be,
                      const int* __restrict__ goff, const int* __restrict__ gcnt,
                      const int* __restrict__ gpack, const float* __restrict__ epsp, int layer,
                      u16* __restrict__ hhg){
  __shared__ float bes[16][128];
  int n=blockIdx.x, c=threadIdx.x;
  for(int i=0;i<16;i++) bes[i][c]=be[i*128+c];
  __syncthreads();
  float acc=0.f;
  int o=goff[n], e=o+gcnt[n];
  for(;o<e;o++){
    int p=gpack[o];
    acc+=fmaxf(b2f(hn[(size_t)(p>>4)*H+c])+bes[p&15][c],0.f);
  }
  hhg[(size_t)n*H+c]=f2b(fmaf(1.f+epsp[layer],b2f(hn[(size_t)n*H+c]),acc));
}

// ---- h_node' = h_node + BN_affine(a_g)
__global__ void k_bnadd(const u16* __restrict__ hn, const u16* __restrict__ ag,
                        const float* __restrict__ bnG, u16* __restrict__ hn2){
  int i=blockIdx.x*blockDim.x+threadIdx.x;
  if(i>=NN*H) return;
  int c=i&127;
  hn2[i]=f2b(b2f(hn[i])+fmaf(b2f(ag[i]),bnG[c],bnG[128+c]));
}

// ---- final pooling
__global__ __launch_bounds__(128) void k_pool(const u16* __restrict__ h, const int* __restrict__ valid,
                      const int* __restrict__ batch, float* __restrict__ oacc){
  __shared__ float cs[2];
  int n=blockIdx.x, c=threadIdx.x;
  if(c<2){
    int s=0;
    for(int j=0;j<32;j++) s+=valid[n*64+c*32+j];
    cs[c]=fmaxf((float)s,1.f);
  }
  __syncthreads();
  size_t base=(size_t)n*64*H;
  float a0=0.f,a1=0.f;
  for(int j=0;j<32;j++){
    a0+=b2f(h[base+(size_t)j*H+c]);
    a1+=b2f(h[base+(size_t)(32+j)*H+c]);
  }
  float nodef=0.5f*(a0/cs[0]+a1/cs[1]);
  atomicAdd(&oacc[batch[n]*H+c],nodef);
}

__global__ void k_out(const float* __restrict__ acc, const int* __restrict__ flag, void* __restrict__ out){
  int i=blockIdx.x*blockDim.x+threadIdx.x;
  if(i>=NGRAPH*H) return;
  if(*flag) ((__hip_bfloat16*)out)[i]=__float2bfloat16(acc[i]);
  else ((float*)out)[i]=acc[i];
}

extern "C" void kernel_launch(void* const* d_in, const int* in_sizes, int n_in,
                              void* d_out, int out_size, void* d_ws, size_t ws_size,
                              hipStream_t stream){
  (void)n_in; (void)out_size;
  int pofs[27]; pofs[0]=0;
  for(int i=0;i<26;i++) pofs[i+1]=pofs[i]+in_sizes[i];
  int ptot=pofs[26];

  char* wsb=(char*)d_ws;
  size_t off=0;
  auto alloc=[&](size_t bytes)->char*{ char* p=wsb+off; off+=(bytes+255)&~(size_t)255; return p; };
  int*   flag =(int*)  alloc(4);
  float* par  =(float*)alloc((size_t)ptot*4);
  u16*   h    =(u16*)  alloc((size_t)SKK*H*2);
  u16*   X    =(u16*)  alloc((size_t)SKK*H*2);
  float* rf   =(float*)alloc((size_t)NN*H*4);
  u16*   hn   =(u16*)  alloc((size_t)NN*H*2);
  u16*   hhg  =(u16*)  alloc((size_t)NN*H*2);
  u16*   tg   =(u16*)  alloc((size_t)NN*H*2);
  u16*   ag   =(u16*)  alloc((size_t)NN*H*2);
  u16*   hn2  =(u16*)  alloc((size_t)NN*H*2);
  u16*   bno  =(u16*)  alloc((size_t)NN*H*2);
  u16*   bb   =(u16*)  alloc((size_t)NN*H*2);
  float* stl  =(float*)alloc(256*4);
  float* stg  =(float*)alloc(256*4);
  float* bnl  =(float*)alloc(256*4);
  float* bnG  =(float*)alloc(256*4);
  float* oacc =(float*)alloc((size_t)NGRAPH*H*4);
  int* ecnt =(int*)alloc(SS*4);
  int* eoff =(int*)alloc(SS*4);
  int* ecur =(int*)alloc(SS*4);
  int* epack=(int*)alloc((size_t)EI*4);
  int* gcnt =(int*)alloc(NN*4);
  int* goff =(int*)alloc(NN*4);
  int* gcur =(int*)alloc(NN*4);
  int* gpack=(int*)alloc((size_t)EG*4);

  if(off>ws_size) return;   // diagnostic: zeros-out => ws too small (vs crash)

  const int* xids =(const int*)d_in[26];
  const int* iei  =(const int*)d_in[27];
  const int* iea  =(const int*)d_in[28];
  const int* gei  =(const int*)d_in[29];
  const int* gea  =(const int*)d_in[30];
  const int* nids =(const int*)d_in[31];
  const int* valid=(const int*)d_in[32];
  const int* batch=(const int*)d_in[33];

  const float* atom=par+pofs[0];
  const float* bond=par+pofs[1];
  const float* rw_w=par+pofs[2];
  const float* rw_b=par+pofs[3];
  const float* rwse=par+pofs[4];
  const float* leps=par+pofs[5];
  const float* lw1 =par+pofs[6];
  const float* lb1 =par+pofs[7];
  const float* lw2 =par+pofs[8];
  const float* lb2 =par+pofs[9];
  const float* lbng=par+pofs[10];
  const float* lbnb=par+pofs[11];
  const float* geps=par+pofs[12];
  const float* gw1 =par+pofs[13];
  const float* gb1 =par+pofs[14];
  const float* gw2 =par+pofs[15];
  const float* gb2 =par+pofs[16];
  const float* gbng=par+pofs[17];
  const float* gbnb=par+pofs[18];
  const float* bcw =par+pofs[19];
  const float* cw1 =par+pofs[20];
  const float* cb1 =par+pofs[21];
  const float* cw2 =par+pofs[22];
  const float* cb2 =par+pofs[23];
  const float* lngp=par+pofs[24];
  const float* lnbp=par+pofs[25];

  k_sniff<<<1,256,0,stream>>>((const u16*)d_in[0], flag);
  CvtArgs ca;
  for(int i=0;i<26;i++){ ca.p[i]=d_in[i]; ca.start[i]=pofs[i]; }
  ca.start[26]=ptot;
  k_convert<<<1024,256,0,stream>>>(ca, flag, par);

  (void)hipMemsetAsync(ecnt,0,SS*4,stream);
  (void)hipMemsetAsync(ecur,0,SS*4,stream);
  (void)hipMemsetAsync(gcnt,0,NN*4,stream);
  (void)hipMemsetAsync(gcur,0,NN*4,stream);
  (void)hipMemsetAsync(oacc,0,NGRAPH*H*4,stream);

  k_hist<<<2048,256,0,stream>>>(iei+EI, EI, 5, ecnt);
  k_scan<<<1,1024,0,stream>>>(ecnt, eoff, SS);
  k_scatter_i<<<2048,256,0,stream>>>(iei, iea, eoff, ecur, epack);
  k_hist<<<512,256,0,stream>>>(gei+EG, EG, 0, gcnt);
  k_scan<<<1,1024,0,stream>>>(gcnt, goff, NN);
  k_scatter_g<<<512,256,0,stream>>>(gei, gea, goff, gcur, gpack);

  k_rwse<<<NN,128,0,stream>>>(rwse, rw_w, rw_b, rf);
  k_h0<<<(SKK*16)/256,256,0,stream>>>(atom, rf, xids, nids, valid, h);

  for(int l=0;l<LNUM;l++){
    (void)hipMemsetAsync(stl,0,256*4,stream);
    (void)hipMemsetAsync(stg,0,256*4,stream);
    k_local_agg<<<SS,128,0,stream>>>(h, bond, eoff, ecnt, epack, leps, l, X);
    k_gemm<1><<<SKK/64,256,0,stream>>>(X, lw1+(size_t)l*H*H, lb1+l*H, X,
        nullptr,nullptr,nullptr,nullptr,nullptr,nullptr,nullptr,nullptr);
    k_gemm<2><<<SKK/64,256,0,stream>>>(X, lw2+(size_t)l*H*H, lb2+l*H, X,
        nullptr,nullptr,nullptr,stl,nullptr,nullptr,nullptr,nullptr);
    k_npool<<<(NN*16)/256,256,0,stream>>>(h, hn);
    k_gagg<<<NN,128,0,stream>>>(hn, bond, goff, gcnt, gpack, geps, l, hhg);
    k_gemm<1><<<NN/64,256,0,stream>>>(hhg, gw1+(size_t)l*H*H, gb1+l*H, tg,
        nullptr,nullptr,nullptr,nullptr,nullptr,nullptr,nullptr,nullptr);
    k_gemm<2><<<NN/64,256,0,stream>>>(tg, gw2+(size_t)l*H*H, gb2+l*H, ag,
        nullptr,nullptr,nullptr,stg,nullptr,nullptr,nullptr,nullptr);
    k_bnfin<<<1,128,0,stream>>>(stl, stg, lbng+l*H, lbnb+l*H, gbng+l*H, gbnb+l*H, bnl, bnG);
    k_bnadd<<<(NN*H+255)/256,256,0,stream>>>(hn, ag, bnG, hn2);
    k_gemm<0><<<NN/64,256,0,stream>>>(hn2, bcw+(size_t)l*H*H, nullptr, bno,
        nullptr,nullptr,nullptr,nullptr,nullptr,nullptr,nullptr,nullptr);
    k_gemm<0><<<NN/64,256,0,stream>>>(bno, cw1+(size_t)l*2*H*H+H*H, nullptr, bb,
        nullptr,nullptr,nullptr,nullptr,nullptr,nullptr,nullptr,nullptr);
    k_gemm<3><<<SKK/64,256,0,stream>>>(X, cw1+(size_t)l*2*H*H, cb1+l*H, X,
        bnl, bnl+128, bb, nullptr,nullptr,nullptr,nullptr,nullptr);
    k_gemm<4><<<SKK/64,256,0,stream>>>(X, cw2+(size_t)l*H*H, cb2+l*H, h,
        nullptr,nullptr,nullptr,nullptr, h, valid, lngp+l*H, lnbp+l*H);
  }
  k_pool<<<NN,128,0,stream>>>(h, valid, batch, oacc);
  k_out<<<(NGRAPH*H+255)/256,256,0,stream>>>(oacc, flag, d_out);
}

// Round 3
// 2143.858 us; speedup vs baseline: 1.4767x; 1.4767x over previous
//
#include <hip/hip_runtime.h>
#include <hip/hip_bf16.h>

#define H 128
#define HH 16384
#define LNUM 4
#define NN 4096
#define SS 8192
#define SKK 262144
#define EI 1048576
#define EG 65536
#define NGRAPH 64

typedef unsigned short u16;
typedef unsigned int u32;
typedef __attribute__((ext_vector_type(8))) short s16x8;
typedef __attribute__((ext_vector_type(4))) float f32x4;

__device__ __forceinline__ float b2f(u32 u){ return __uint_as_float(u<<16); }
__device__ __forceinline__ u16 f2b(float f){
  union { __hip_bfloat16 b; u16 u; } x;
  x.b=__float2bfloat16(f);
  return x.u;
}
__device__ __forceinline__ void unp8(uint4 v, float* f){
  f[0]=b2f(v.x&0xFFFF); f[1]=b2f(v.x>>16);
  f[2]=b2f(v.y&0xFFFF); f[3]=b2f(v.y>>16);
  f[4]=b2f(v.z&0xFFFF); f[5]=b2f(v.z>>16);
  f[6]=b2f(v.w&0xFFFF); f[7]=b2f(v.w>>16);
}
__device__ __forceinline__ uint4 pk8(const float* f){
  uint4 r;
  r.x=(u32)f2b(f[0])|((u32)f2b(f[1])<<16);
  r.y=(u32)f2b(f[2])|((u32)f2b(f[3])<<16);
  r.z=(u32)f2b(f[4])|((u32)f2b(f[5])<<16);
  r.w=(u32)f2b(f[6])|((u32)f2b(f[7])<<16);
  return r;
}

struct CvtArgs {
  const void* p[26];
  int start[27];
};
struct TransArgs { int src[28]; };

// ---- dtype sniff
__global__ void k_sniff(const u16* __restrict__ a, int* __restrict__ flag){
  __shared__ int cnt;
  if(threadIdx.x==0) cnt=0;
  __syncthreads();
  int big=0;
  for(int i=threadIdx.x;i<2048;i+=256){
    int e=(a[i]>>7)&0xFF;
    if(e>=127) big++;
  }
  atomicAdd(&cnt,big);
  __syncthreads();
  if(threadIdx.x==0) *flag=(cnt<16)?1:0;
}

__global__ void k_convert(CvtArgs args, const int* __restrict__ flag, float* __restrict__ dst){
  int fl=*flag;
  int total=args.start[26];
  for(int i=blockIdx.x*blockDim.x+threadIdx.x;i<total;i+=gridDim.x*blockDim.x){
    int a=0;
    while(args.start[a+1]<=i) a++;
    int j=i-args.start[a];
    float v;
    if(fl) v=b2f(((const u16*)args.p[a])[j]);
    else   v=((const float*)args.p[a])[j];
    dst[i]=v;
  }
}

// ---- static weights: f32 [K][N] -> bf16 W^T [N][K]
__global__ __launch_bounds__(256) void k_trans(const float* __restrict__ par, TransArgs ta, u16* __restrict__ wt){
  const float* s=par+ta.src[blockIdx.x];
  u16* d=wt+(size_t)blockIdx.x*HH;
  for(int i=threadIdx.x;i<HH;i+=256){
    int n=i>>7, k=i&127;
    d[i]=f2b(s[(size_t)k*H+n]);
  }
}

// ---- fold BN affine into cw1_top: Wt3[n][k]=s[k]*W[k][n], bias3[c]=cb1[c]+sum_k t[k]W[k][c]
__global__ __launch_bounds__(128) void k_prepw3(const float* __restrict__ w, const float* __restrict__ cb1,
                        const float* __restrict__ bnl, u16* __restrict__ wt3, float* __restrict__ bias3){
  __shared__ float red[128];
  int c=blockIdx.x, k=threadIdx.x;
  float wv=w[(size_t)k*H+c];
  wt3[(size_t)c*H+k]=f2b(bnl[k]*wv);
  red[k]=bnl[128+k]*wv;
  __syncthreads();
  for(int d=64;d>0;d>>=1){ if(k<d) red[k]+=red[k+d]; __syncthreads(); }
  if(k==0) bias3[c]=cb1[c]+red[0];
}

// ---- edge bucketing
__global__ void k_hist(const int* __restrict__ idx, int n, int shift, int* __restrict__ cnt){
  for(int i=blockIdx.x*blockDim.x+threadIdx.x;i<n;i+=gridDim.x*blockDim.x)
    atomicAdd(&cnt[idx[i]>>shift],1);
}

__global__ void k_scan(const int* __restrict__ cnt, int* __restrict__ off, int nbins){
  __shared__ int ts[1024];
  int t=threadIdx.x;
  int per=nbins>>10;
  int base=t*per;
  int s=0;
  for(int j=0;j<per;j++) s+=cnt[base+j];
  ts[t]=s;
  __syncthreads();
  for(int d=1;d<1024;d<<=1){
    int v=(t>=d)?ts[t-d]:0;
    __syncthreads();
    ts[t]+=v;
    __syncthreads();
  }
  int ex=(t==0)?0:ts[t-1];
  for(int j=0;j<per;j++){ off[base+j]=ex; ex+=cnt[base+j]; }
}

__global__ void k_scatter_i(const int* __restrict__ ei, const int* __restrict__ ea,
                            const int* __restrict__ off, int* __restrict__ cur, int* __restrict__ pack){
  for(int i=blockIdx.x*blockDim.x+threadIdx.x;i<EI;i+=gridDim.x*blockDim.x){
    int s=ei[i], d=ei[EI+i];
    int sub=d>>5;
    int pos=off[sub]+atomicAdd(&cur[sub],1);
    pack[pos]=((s&31)<<9)|((d&31)<<4)|(ea[i]&15);
  }
}

__global__ void k_scatter_g(const int* __restrict__ ei, const int* __restrict__ ea,
                            const int* __restrict__ off, int* __restrict__ cur, int* __restrict__ pack){
  for(int i=blockIdx.x*blockDim.x+threadIdx.x;i<EG;i+=gridDim.x*blockDim.x){
    int s=ei[i], d=ei[EG+i];
    int pos=off[d]+atomicAdd(&cur[d],1);
    pack[pos]=(s<<4)|(ea[i]&15);
  }
}

// ---- rf = relu(rwse @ rwse_w + rwse_b)
__global__ __launch_bounds__(128) void k_rwse(const float* __restrict__ rwse, const float* __restrict__ w,
                      const float* __restrict__ b, float* __restrict__ rf){
  __shared__ float ws[16*128];
  __shared__ float rv[16];
  int n=blockIdx.x, c=threadIdx.x;
  for(int i=c;i<2048;i+=128) ws[i]=w[i];
  if(c<16) rv[c]=rwse[n*16+c];
  __syncthreads();
  float acc=b[c];
  for(int j=0;j<16;j++) acc=fmaf(rv[j],ws[j*128+c],acc);
  rf[(size_t)n*H+c]=fmaxf(acc,0.f);
}

// ---- h0
__global__ void k_h0(const float* __restrict__ atom, const float* __restrict__ rf,
                     const int* __restrict__ xids, const int* __restrict__ nids,
                     const int* __restrict__ valid, u16* __restrict__ h){
  int i=blockIdx.x*blockDim.x+threadIdx.x;
  if(i>=SKK*16) return;
  int r=i>>4, q=i&15;
  const float4* ap=(const float4*)(atom+(size_t)xids[r]*H)+q*2;
  const float4* bp=(const float4*)(rf+(size_t)nids[r]*H)+q*2;
  float4 a0=ap[0],a1=ap[1],b0=bp[0],b1=bp[1];
  float vm=valid[r]?1.f:0.f;
  float f[8]={(a0.x+b0.x)*vm,(a0.y+b0.y)*vm,(a0.z+b0.z)*vm,(a0.w+b0.w)*vm,
              (a1.x+b1.x)*vm,(a1.y+b1.y)*vm,(a1.z+b1.z)*vm,(a1.w+b1.w)*vm};
  ((uint4*)h)[i]=pk8(f);
}

// ---- local GINE aggregation per subgraph
__global__ __launch_bounds__(128) void k_local_agg(const u16* __restrict__ h, const float* __restrict__ be,
                           const int* __restrict__ eoff, const int* __restrict__ ecnt,
                           const int* __restrict__ epack, const float* __restrict__ epsp, int layer,
                           u16* __restrict__ hh){
  __shared__ float hs[32][128];
  __shared__ float ag[32][128];
  __shared__ float bes[16][128];
  int sub=blockIdx.x, c=threadIdx.x;
  size_t base=(size_t)sub*32*H;
  for(int r=0;r<32;r++){ hs[r][c]=b2f(h[base+r*H+c]); ag[r][c]=0.f; }
  for(int i=0;i<16;i++) bes[i][c]=be[i*128+c];
  __syncthreads();
  int o=eoff[sub], e=o+ecnt[sub];
  for(;o<e;o++){
    int p=epack[o];
    int sl=p>>9, dl=(p>>4)&31, ea=p&15;
    ag[dl][c]+=fmaxf(hs[sl][c]+bes[ea][c],0.f);
  }
  __syncthreads();
  float ep=1.f+epsp[layer];
  for(int r=0;r<32;r++) hh[base+r*H+c]=f2b(fmaf(ep,hs[r][c],ag[r][c]));
}

// ==== MFMA GEMM: rows x [128->128], A bf16 row-major, Wt bf16 [N][K]
// MODE 0: out = A@W            MODE 1: relu(A@W+b)
// MODE 2: relu(A@W+b) + column stats
// MODE 3: gelu(A@W + b + rowbias[node])   (BN affine pre-folded into W,b)
// MODE 4: LN(A@W+b); out=(res+v)*valid
template<int MODE>
__global__ __launch_bounds__(256) void k_mgemm(
    const u16* __restrict__ A, const u16* __restrict__ Wt,
    const float* __restrict__ bias, u16* __restrict__ out,
    const u16* __restrict__ rowbias,
    float* __restrict__ stats,
    const u16* __restrict__ res, const int* __restrict__ validv,
    const float* __restrict__ lng, const float* __restrict__ lnb)
{
  __shared__ float sst[256];
  int t=threadIdx.x;
  if(MODE==2){ if(t<256) sst[t]=0.f; __syncthreads(); }
  int wave=t>>6, lane=t&63;
  int lr=lane&15, lk=lane>>4;
  int rowW=blockIdx.x*128+wave*32;

  f32x4 acc[2][8];
  #pragma unroll
  for(int m=0;m<2;m++)
    #pragma unroll
    for(int n=0;n<8;n++) acc[m][n]=(f32x4){0.f,0.f,0.f,0.f};

  const s16x8* A0=(const s16x8*)(A+(size_t)(rowW+lr)*H);
  const s16x8* A1=(const s16x8*)(A+(size_t)(rowW+16+lr)*H);

  #pragma unroll
  for(int kc=0;kc<4;kc++){
    s16x8 af0=A0[kc*4+lk];
    s16x8 af1=A1[kc*4+lk];
    #pragma unroll
    for(int n=0;n<8;n++){
      s16x8 bf=*(const s16x8*)(Wt+(size_t)(n*16+lr)*H+kc*32+lk*8);
      acc[0][n]=__builtin_amdgcn_mfma_f32_16x16x32_bf16(af0,bf,acc[0][n],0,0,0);
      acc[1][n]=__builtin_amdgcn_mfma_f32_16x16x32_bf16(af1,bf,acc[1][n],0,0,0);
    }
  }

  #pragma unroll
  for(int m=0;m<2;m++){
    int rbase=rowW+m*16;
    if(MODE==4){
      float rs[4]={0.f,0.f,0.f,0.f}, rq[4]={0.f,0.f,0.f,0.f};
      #pragma unroll
      for(int n=0;n<8;n++){
        float bv=bias[n*16+lr];
        #pragma unroll
        for(int j=0;j<4;j++){
          float v=acc[m][n][j]+bv;
          acc[m][n][j]=v;
          rs[j]+=v; rq[j]+=v*v;
        }
      }
      #pragma unroll
      for(int j=0;j<4;j++){
        #pragma unroll
        for(int d=1;d<16;d<<=1){
          rs[j]+=__shfl_xor(rs[j],d);
          rq[j]+=__shfl_xor(rq[j],d);
        }
      }
      float mu[4],rsig[4],vm[4];
      #pragma unroll
      for(int j=0;j<4;j++){
        mu[j]=rs[j]*(1.f/128.f);
        float va=rq[j]*(1.f/128.f)-mu[j]*mu[j];
        rsig[j]=rsqrtf(va+1e-5f);
        vm[j]=validv[rbase+lk*4+j]?1.f:0.f;
      }
      #pragma unroll
      for(int n=0;n<8;n++){
        int c=n*16+lr;
        float g=lng[c], be=lnb[c];
        #pragma unroll
        for(int j=0;j<4;j++){
          int rg=rbase+lk*4+j;
          float v=(acc[m][n][j]-mu[j])*rsig[j]*g+be;
          out[(size_t)rg*H+c]=f2b((b2f(res[(size_t)rg*H+c])+v)*vm[j]);
        }
      }
    } else {
      int nb=rowW>>6;
      #pragma unroll
      for(int n=0;n<8;n++){
        int c=n*16+lr;
        float bv=bias?bias[c]:0.f;
        float v[4];
        #pragma unroll
        for(int j=0;j<4;j++) v[j]=acc[m][n][j]+bv;
        if(MODE==3){
          float rb=b2f(rowbias[(size_t)nb*H+c]);
          #pragma unroll
          for(int j=0;j<4;j++){
            float x=v[j]+rb;
            v[j]=0.5f*x*(1.f+erff(x*0.70710678118654752f));
          }
        }
        if(MODE==1||MODE==2){
          #pragma unroll
          for(int j=0;j<4;j++) v[j]=fmaxf(v[j],0.f);
        }
        #pragma unroll
        for(int j=0;j<4;j++) out[(size_t)(rbase+lk*4+j)*H+c]=f2b(v[j]);
        if(MODE==2){
          float s=v[0]+v[1]+v[2]+v[3];
          float q=v[0]*v[0]+v[1]*v[1]+v[2]*v[2]+v[3]*v[3];
          s+=__shfl_xor(s,16); s+=__shfl_xor(s,32);
          q+=__shfl_xor(q,16); q+=__shfl_xor(q,32);
          if(lane<16){
            atomicAdd(&sst[c],s);
            atomicAdd(&sst[128+c],q);
          }
        }
      }
    }
  }
  if(MODE==2){
    __syncthreads();
    if(t<256) atomicAdd(&stats[t],sst[t]);
  }
}

// ---- BN stats -> per-column affine
__global__ void k_bnfin(const float* __restrict__ stl, const float* __restrict__ stg,
                        const float* __restrict__ gl, const float* __restrict__ bl,
                        const float* __restrict__ gg, const float* __restrict__ bg,
                        float* __restrict__ bnl, float* __restrict__ bnG){
  int c=threadIdx.x;
  {
    float mu=stl[c]*(1.f/262144.f);
    float var=stl[128+c]*(1.f/262144.f)-mu*mu;
    float s=gl[c]*rsqrtf(var+1e-5f);
    bnl[c]=s; bnl[128+c]=bl[c]-mu*s;
  }
  {
    float mu=stg[c]*(1.f/4096.f);
    float var=stg[128+c]*(1.f/4096.f)-mu*mu;
    float s=gg[c]*rsqrtf(var+1e-5f);
    bnG[c]=s; bnG[128+c]=bg[c]-mu*s;
  }
}

// ---- h_node = mean of two root rows
__global__ void k_npool(const u16* __restrict__ h, u16* __restrict__ hn){
  int i=blockIdx.x*blockDim.x+threadIdx.x;
  if(i>=NN*16) return;
  int n=i>>4, q=i&15;
  const uint4* hp=(const uint4*)h;
  float a[8],b[8],o[8];
  unp8(hp[(size_t)n*1024+q],a);
  unp8(hp[(size_t)n*1024+512+q],b);
  #pragma unroll
  for(int e=0;e<8;e++) o[e]=(a[e]+b[e])*0.5f;
  ((uint4*)hn)[i]=pk8(o);
}

// ---- global GINE aggregation per node
__global__ __launch_bounds__(128) void k_gagg(const u16* __restrict__ hn, const float* __restrict__ be,
                      const int* __restrict__ goff, const int* __restrict__ gcnt,
                      const int* __restrict__ gpack, const float* __restrict__ epsp, int layer,
                      u16* __restrict__ hhg){
  __shared__ float bes[16][128];
  int n=blockIdx.x, c=threadIdx.x;
  for(int i=0;i<16;i++) bes[i][c]=be[i*128+c];
  __syncthreads();
  float acc=0.f;
  int o=goff[n], e=o+gcnt[n];
  for(;o<e;o++){
    int p=gpack[o];
    acc+=fmaxf(b2f(hn[(size_t)(p>>4)*H+c])+bes[p&15][c],0.f);
  }
  hhg[(size_t)n*H+c]=f2b(fmaf(1.f+epsp[layer],b2f(hn[(size_t)n*H+c]),acc));
}

// ---- h_node' = h_node + BN_affine(a_g)
__global__ void k_bnadd(const u16* __restrict__ hn, const u16* __restrict__ ag,
                        const float* __restrict__ bnG, u16* __restrict__ hn2){
  int i=blockIdx.x*blockDim.x+threadIdx.x;
  if(i>=NN*H) return;
  int c=i&127;
  hn2[i]=f2b(b2f(hn[i])+fmaf(b2f(ag[i]),bnG[c],bnG[128+c]));
}

// ---- final pooling
__global__ __launch_bounds__(128) void k_pool(const u16* __restrict__ h, const int* __restrict__ valid,
                      const int* __restrict__ batch, float* __restrict__ oacc){
  __shared__ float cs[2];
  int n=blockIdx.x, c=threadIdx.x;
  if(c<2){
    int s=0;
    for(int j=0;j<32;j++) s+=valid[n*64+c*32+j];
    cs[c]=fmaxf((float)s,1.f);
  }
  __syncthreads();
  size_t base=(size_t)n*64*H;
  float a0=0.f,a1=0.f;
  for(int j=0;j<32;j++){
    a0+=b2f(h[base+(size_t)j*H+c]);
    a1+=b2f(h[base+(size_t)(32+j)*H+c]);
  }
  float nodef=0.5f*(a0/cs[0]+a1/cs[1]);
  atomicAdd(&oacc[batch[n]*H+c],nodef);
}

__global__ void k_out(const float* __restrict__ acc, const int* __restrict__ flag, void* __restrict__ out){
  int i=blockIdx.x*blockDim.x+threadIdx.x;
  if(i>=NGRAPH*H) return;
  if(*flag) ((__hip_bfloat16*)out)[i]=__float2bfloat16(acc[i]);
  else ((float*)out)[i]=acc[i];
}

extern "C" void kernel_launch(void* const* d_in, const int* in_sizes, int n_in,
                              void* d_out, int out_size, void* d_ws, size_t ws_size,
                              hipStream_t stream){
  (void)n_in; (void)out_size;
  int pofs[27]; pofs[0]=0;
  for(int i=0;i<26;i++) pofs[i+1]=pofs[i]+in_sizes[i];
  int ptot=pofs[26];

  char* wsb=(char*)d_ws;
  size_t off=0;
  auto alloc=[&](size_t bytes)->char*{ char* p=wsb+off; off+=(bytes+255)&~(size_t)255; return p; };
  int*   flag =(int*)  alloc(4);
  float* par  =(float*)alloc((size_t)ptot*4);
  u16*   h    =(u16*)  alloc((size_t)SKK*H*2);
  u16*   X    =(u16*)  alloc((size_t)SKK*H*2);
  u16*   wt   =(u16*)  alloc((size_t)28*HH*2);
  u16*   wt3  =(u16*)  alloc((size_t)HH*2);
  float* bias3=(float*)alloc(H*4);
  float* rf   =(float*)alloc((size_t)NN*H*4);
  u16*   hn   =(u16*)  alloc((size_t)NN*H*2);
  u16*   hhg  =(u16*)  alloc((size_t)NN*H*2);
  u16*   tg   =(u16*)  alloc((size_t)NN*H*2);
  u16*   ag   =(u16*)  alloc((size_t)NN*H*2);
  u16*   hn2  =(u16*)  alloc((size_t)NN*H*2);
  u16*   bno  =(u16*)  alloc((size_t)NN*H*2);
  u16*   bb   =(u16*)  alloc((size_t)NN*H*2);
  float* stl  =(float*)alloc(256*4);
  float* stg  =(float*)alloc(256*4);
  float* bnl  =(float*)alloc(256*4);
  float* bnG  =(float*)alloc(256*4);
  float* oacc =(float*)alloc((size_t)NGRAPH*H*4);
  int* ecnt =(int*)alloc(SS*4);
  int* eoff =(int*)alloc(SS*4);
  int* ecur =(int*)alloc(SS*4);
  int* epack=(int*)alloc((size_t)EI*4);
  int* gcnt =(int*)alloc(NN*4);
  int* goff =(int*)alloc(NN*4);
  int* gcur =(int*)alloc(NN*4);
  int* gpack=(int*)alloc((size_t)EG*4);

  if(off>ws_size) return;

  const int* xids =(const int*)d_in[26];
  const int* iei  =(const int*)d_in[27];
  const int* iea  =(const int*)d_in[28];
  const int* gei  =(const int*)d_in[29];
  const int* gea  =(const int*)d_in[30];
  const int* nids =(const int*)d_in[31];
  const int* valid=(const int*)d_in[32];
  const int* batch=(const int*)d_in[33];

  const float* atom=par+pofs[0];
  const float* bond=par+pofs[1];
  const float* rw_w=par+pofs[2];
  const float* rw_b=par+pofs[3];
  const float* rwse=par+pofs[4];
  const float* leps=par+pofs[5];
  const float* lb1 =par+pofs[7];
  const float* lb2 =par+pofs[9];
  const float* lbng=par+pofs[10];
  const float* lbnb=par+pofs[11];
  const float* geps=par+pofs[12];
  const float* gb1 =par+pofs[14];
  const float* gb2 =par+pofs[16];
  const float* gbng=par+pofs[17];
  const float* gbnb=par+pofs[18];
  const float* cw1 =par+pofs[20];
  const float* cb1 =par+pofs[21];
  const float* cb2 =par+pofs[23];
  const float* lngp=par+pofs[24];
  const float* lnbp=par+pofs[25];

  k_sniff<<<1,256,0,stream>>>((const u16*)d_in[0], flag);
  CvtArgs ca;
  for(int i=0;i<26;i++){ ca.p[i]=d_in[i]; ca.start[i]=pofs[i]; }
  ca.start[26]=ptot;
  k_convert<<<1024,256,0,stream>>>(ca, flag, par);

  TransArgs ta;
  for(int l=0;l<LNUM;l++){
    ta.src[l*7+0]=pofs[6]+l*HH;           // lw1
    ta.src[l*7+1]=pofs[8]+l*HH;           // lw2
    ta.src[l*7+2]=pofs[13]+l*HH;          // gw1
    ta.src[l*7+3]=pofs[15]+l*HH;          // gw2
    ta.src[l*7+4]=pofs[19]+l*HH;          // bcw
    ta.src[l*7+5]=pofs[20]+l*2*HH+HH;     // cw1 bottom half
    ta.src[l*7+6]=pofs[22]+l*HH;          // cw2
  }
  k_trans<<<28,256,0,stream>>>(par, ta, wt);

  (void)hipMemsetAsync(ecnt,0,SS*4,stream);
  (void)hipMemsetAsync(ecur,0,SS*4,stream);
  (void)hipMemsetAsync(gcnt,0,NN*4,stream);
  (void)hipMemsetAsync(gcur,0,NN*4,stream);
  (void)hipMemsetAsync(oacc,0,NGRAPH*H*4,stream);

  k_hist<<<2048,256,0,stream>>>(iei+EI, EI, 5, ecnt);
  k_scan<<<1,1024,0,stream>>>(ecnt, eoff, SS);
  k_scatter_i<<<2048,256,0,stream>>>(iei, iea, eoff, ecur, epack);
  k_hist<<<512,256,0,stream>>>(gei+EG, EG, 0, gcnt);
  k_scan<<<1,1024,0,stream>>>(gcnt, goff, NN);
  k_scatter_g<<<512,256,0,stream>>>(gei, gea, goff, gcur, gpack);

  k_rwse<<<NN,128,0,stream>>>(rwse, rw_w, rw_b, rf);
  k_h0<<<(SKK*16)/256,256,0,stream>>>(atom, rf, xids, nids, valid, h);

  for(int l=0;l<LNUM;l++){
    (void)hipMemsetAsync(stl,0,256*4,stream);
    (void)hipMemsetAsync(stg,0,256*4,stream);
    k_local_agg<<<SS,128,0,stream>>>(h, bond, eoff, ecnt, epack, leps, l, X);
    k_mgemm<1><<<SKK/128,256,0,stream>>>(X, wt+(size_t)(l*7+0)*HH, lb1+l*H, X,
        nullptr,nullptr,nullptr,nullptr,nullptr,nullptr);
    k_mgemm<2><<<SKK/128,256,0,stream>>>(X, wt+(size_t)(l*7+1)*HH, lb2+l*H, X,
        nullptr,stl,nullptr,nullptr,nullptr,nullptr);
    k_npool<<<(NN*16)/256,256,0,stream>>>(h, hn);
    k_gagg<<<NN,128,0,stream>>>(hn, bond, goff, gcnt, gpack, geps, l, hhg);
    k_mgemm<1><<<NN/128,256,0,stream>>>(hhg, wt+(size_t)(l*7+2)*HH, gb1+l*H, tg,
        nullptr,nullptr,nullptr,nullptr,nullptr,nullptr);
    k_mgemm<2><<<NN/128,256,0,stream>>>(tg, wt+(size_t)(l*7+3)*HH, gb2+l*H, ag,
        nullptr,stg,nullptr,nullptr,nullptr,nullptr);
    k_bnfin<<<1,128,0,stream>>>(stl, stg, lbng+l*H, lbnb+l*H, gbng+l*H, gbnb+l*H, bnl, bnG);
    k_bnadd<<<(NN*H+255)/256,256,0,stream>>>(hn, ag, bnG, hn2);
    k_mgemm<0><<<NN/128,256,0,stream>>>(hn2, wt+(size_t)(l*7+4)*HH, nullptr, bno,
        nullptr,nullptr,nullptr,nullptr,nullptr,nullptr);
    k_mgemm<0><<<NN/128,256,0,stream>>>(bno, wt+(size_t)(l*7+5)*HH, nullptr, bb,
        nullptr,nullptr,nullptr,nullptr,nullptr,nullptr);
    k_prepw3<<<128,128,0,stream>>>(cw1+(size_t)l*2*HH, cb1+l*H, bnl, wt3, bias3);
    k_mgemm<3><<<SKK/128,256,0,stream>>>(X, wt3, bias3, X,
        bb,nullptr,nullptr,nullptr,nullptr,nullptr);
    k_mgemm<4><<<SKK/128,256,0,stream>>>(X, wt+(size_t)(l*7+6)*HH, cb2+l*H, h,
        nullptr,nullptr, h, valid, lngp+l*H, lnbp+l*H);
  }
  k_pool<<<NN,128,0,stream>>>(h, valid, batch, oacc);
  k_out<<<(NGRAPH*H+255)/256,256,0,stream>>>(oacc, flag, d_out);
}